// Round 8
// baseline (364.093 us; speedup 1.0000x reference)
//
#include <hip/hip_runtime.h>

typedef unsigned short u16;
typedef unsigned int u32;
typedef unsigned long long u64;
typedef __bf16 bf16x8 __attribute__((ext_vector_type(8)));
typedef float f32x4 __attribute__((ext_vector_type(4)));

__device__ __forceinline__ float b2f(u16 u) {
    unsigned int x = ((unsigned int)u) << 16;
    return __builtin_bit_cast(float, x);
}
__device__ __forceinline__ u16 f2b(float f) {
    unsigned int u = __builtin_bit_cast(unsigned int, f);
    unsigned int r = (u + 0x7FFFu + ((u >> 16) & 1u)) >> 16;
    return (u16)r;
}
__device__ __forceinline__ unsigned int pack2(float a, float b) {
    return (unsigned int)f2b(a) | ((unsigned int)f2b(b) << 16);
}
__device__ __forceinline__ float fast_rcp(float x) { return __builtin_amdgcn_rcpf(x); }
__device__ __forceinline__ float fast_tanh(float x) {
    float e = __expf(2.f * x);
    return 1.f - 2.f * fast_rcp(e + 1.f);
}
__device__ __forceinline__ float fast_sig(float x) {
    float e = __expf(-x);
    return fast_rcp(1.f + e);
}

// ---------------- fused prep: casts + xfull + 4x transpose ------------------
__launch_bounds__(256)
__global__ void k_prep(const float* __restrict__ attn_mem, u16* __restrict__ amem_bf,
                       const float* __restrict__ w_ih, u16* __restrict__ wih_bf,
                       const float* __restrict__ w_hh, u16* __restrict__ whh_bf,
                       const float* __restrict__ lstm_in, const float* __restrict__ init_i,
                       u16* __restrict__ xfull,
                       const float* s0, const float* s1, const float* s2, const float* s3,
                       u16* d0, u16* d1, u16* d2, u16* d3) {
    __shared__ float tile[32][33];
    int bid = blockIdx.x;
    int tid = threadIdx.x;
    if (bid < 4096) {
        const float* s;
        u16* d;
        int i;
        if (bid < 2048) { s = attn_mem; d = amem_bf; i = bid * 256 + tid; }
        else if (bid < 3072) { s = w_ih; d = wih_bf; i = (bid - 2048) * 256 + tid; }
        else { s = w_hh; d = whh_bf; i = (bid - 3072) * 256 + tid; }
        float4 a = ((const float4*)s)[i];
        uint2 p;
        p.x = pack2(a.x, a.y);
        p.y = pack2(a.z, a.w);
        ((uint2*)d)[i] = p;
    } else if (bid < 4608) {
        int idx = (bid - 4096) * 256 + tid;
        int c = idx & 127;
        int t = (idx >> 7) & 31;
        int b = idx >> 12;
        const float4* src = (t == 0) ? ((const float4*)init_i) + c
                                     : ((const float4*)lstm_in) + ((b * 31 + (t - 1)) * 128 + c);
        float4 a = *src;
        uint2 p;
        p.x = pack2(a.x, a.y);
        p.y = pack2(a.z, a.w);
        ((uint2*)xfull)[idx] = p;
    } else {
        int local = bid - 4608;
        int z = local >> 8, rem = local & 255;
        int by = (rem >> 4) * 32, bx = (rem & 15) * 32;
        const float* s;
        u16* d;
        switch (z) {
            case 0: s = s0; d = d0; break;
            case 1: s = s1; d = d1; break;
            case 2: s = s2; d = d2; break;
            default: s = s3; d = d3; break;
        }
        int tx = tid & 31, ty = tid >> 5;
        for (int i = 0; i < 32; i += 8) tile[ty + i][tx] = s[(by + ty + i) * 512 + bx + tx];
        __syncthreads();
        for (int i = 0; i < 32; i += 8) d[(bx + ty + i) * 512 + by + tx] = f2b(tile[tx][ty + i]);
    }
}

// ---------------- standalone GEMM (K=512) ----------------------------------
template <bool BF16OUT>
__launch_bounds__(256)
__global__ void k_gemm(const u16* __restrict__ A, const u16* __restrict__ Bt,
                       void* __restrict__ Cv, int GN,
                       const float* __restrict__ bias1, const float* __restrict__ bias2) {
    __shared__ u16 As[64][40];
    __shared__ u16 Bs[64][40];
    int m0 = blockIdx.y * 64, n0 = blockIdx.x * 64;
    int tid = threadIdx.x;
    int lane = tid & 63, w = tid >> 6;
    int wm = w >> 1, wn = w & 1;
    int l15 = lane & 15, quad = lane >> 4;
    f32x4 acc[2][2] = {};
    int ar = tid >> 2, ac = (tid & 3) * 8;
    const u16* Ap = A + (m0 + ar) * 512 + ac;
    const u16* Bp = Bt + (n0 + ar) * 512 + ac;
    for (int kt = 0; kt < 16; ++kt) {
        uint4 av = *(const uint4*)(Ap + kt * 32);
        uint4 bv = *(const uint4*)(Bp + kt * 32);
        __syncthreads();
        *(uint4*)&As[ar][ac] = av;
        *(uint4*)&Bs[ar][ac] = bv;
        __syncthreads();
        bf16x8 a0 = *(const bf16x8*)&As[wm * 32 + l15][quad * 8];
        bf16x8 a1 = *(const bf16x8*)&As[wm * 32 + 16 + l15][quad * 8];
        bf16x8 b0 = *(const bf16x8*)&Bs[wn * 32 + l15][quad * 8];
        bf16x8 b1 = *(const bf16x8*)&Bs[wn * 32 + 16 + l15][quad * 8];
        acc[0][0] = __builtin_amdgcn_mfma_f32_16x16x32_bf16(a0, b0, acc[0][0], 0, 0, 0);
        acc[0][1] = __builtin_amdgcn_mfma_f32_16x16x32_bf16(a0, b1, acc[0][1], 0, 0, 0);
        acc[1][0] = __builtin_amdgcn_mfma_f32_16x16x32_bf16(a1, b0, acc[1][0], 0, 0, 0);
        acc[1][1] = __builtin_amdgcn_mfma_f32_16x16x32_bf16(a1, b1, acc[1][1], 0, 0, 0);
    }
    for (int ai = 0; ai < 2; ++ai)
        for (int bi = 0; bi < 2; ++bi) {
            int row = m0 + wm * 32 + ai * 16 + quad * 4;
            int col = n0 + wn * 32 + bi * 16 + l15;
            float bias = 0.f;
            if (bias1) bias = bias1[col] + bias2[col];
            if constexpr (BF16OUT) {
                u16* C = (u16*)Cv;
                for (int r = 0; r < 4; ++r) C[(row + r) * GN + col] = f2b(acc[ai][bi][r] + bias);
            } else {
                float* C = (float*)Cv;
                for (int r = 0; r < 4; ++r) C[(row + r) * GN + col] = acc[ai][bi][r] + bias;
            }
        }
}

// ---------------- both feat GEMMs in one launch: grid (8, 128) -------------
__launch_bounds__(256)
__global__ void k_feat(const u16* __restrict__ A,
                       const u16* __restrict__ B0, const u16* __restrict__ B1,
                       u16* __restrict__ C0, u16* __restrict__ C1) {
    __shared__ u16 As[64][40];
    __shared__ u16 Bs[64][40];
    int by = blockIdx.y;
    const u16* Bt;
    u16* C;
    int m0;
    if (by < 64) { Bt = B0; C = C0; m0 = by * 64; }
    else { Bt = B1; C = C1; m0 = (by - 64) * 64; }
    int n0 = blockIdx.x * 64;
    int tid = threadIdx.x;
    int lane = tid & 63, w = tid >> 6;
    int wm = w >> 1, wn = w & 1;
    int l15 = lane & 15, quad = lane >> 4;
    f32x4 acc[2][2] = {};
    int ar = tid >> 2, ac = (tid & 3) * 8;
    const u16* Ap = A + (m0 + ar) * 512 + ac;
    const u16* Bp = Bt + (n0 + ar) * 512 + ac;
    for (int kt = 0; kt < 16; ++kt) {
        uint4 av = *(const uint4*)(Ap + kt * 32);
        uint4 bv = *(const uint4*)(Bp + kt * 32);
        __syncthreads();
        *(uint4*)&As[ar][ac] = av;
        *(uint4*)&Bs[ar][ac] = bv;
        __syncthreads();
        bf16x8 a0 = *(const bf16x8*)&As[wm * 32 + l15][quad * 8];
        bf16x8 a1 = *(const bf16x8*)&As[wm * 32 + 16 + l15][quad * 8];
        bf16x8 b0 = *(const bf16x8*)&Bs[wn * 32 + l15][quad * 8];
        bf16x8 b1 = *(const bf16x8*)&Bs[wn * 32 + 16 + l15][quad * 8];
        acc[0][0] = __builtin_amdgcn_mfma_f32_16x16x32_bf16(a0, b0, acc[0][0], 0, 0, 0);
        acc[0][1] = __builtin_amdgcn_mfma_f32_16x16x32_bf16(a0, b1, acc[0][1], 0, 0, 0);
        acc[1][0] = __builtin_amdgcn_mfma_f32_16x16x32_bf16(a1, b0, acc[1][0], 0, 0, 0);
        acc[1][1] = __builtin_amdgcn_mfma_f32_16x16x32_bf16(a1, b1, acc[1][1], 0, 0, 0);
    }
    for (int ai = 0; ai < 2; ++ai)
        for (int bi = 0; bi < 2; ++bi) {
            int row = m0 + wm * 32 + ai * 16 + quad * 4;
            int col = n0 + wn * 32 + bi * 16 + l15;
            for (int r = 0; r < 4; ++r) C[(row + r) * 512 + col] = f2b(acc[ai][bi][r]);
        }
}

// ---------------- persistent LSTM, tagged-data exchange --------------------
// 64 blocks x 256. Block owns k-cols [bid*8,bid*8+8) of all 4 gates.
// hbuf32: [2][64 src][256] u32, each u32 = (tag<<16) | bf16(h).
// Data IS the flag: readers poll slots until tag==t+1. One visibility trip.
// Monotone tags + double parity make exact-match safe; 0xAA poison never
// matches a tag <= 32, so no buffer init is needed.
__launch_bounds__(256, 1)
__global__ void k_lstm3(const u16* __restrict__ w_hh_bf, const float* __restrict__ xw,
                        const float* __restrict__ init_h, const float* __restrict__ init_c,
                        u16* __restrict__ query, u32* __restrict__ hbuf32) {
    __shared__ u16 Bw[32][520];
    __shared__ u16 Ah[32][520];
    __shared__ float gl[32][33];
    int tid = threadIdx.x;
    int k0 = blockIdx.x * 8;
    int lane = tid & 63, w = tid >> 6;
    int mi = w >> 1, ni = w & 1;
    int l15 = lane & 15, quad = lane >> 4;
    int row = tid >> 3, seg = tid & 7;
    // stage w_hh slice (local col r <-> w_hh row (r>>3)*512 + k0 + (r&7))
    {
        int j = (row >> 3) * 512 + k0 + (row & 7);
        const uint4* src = (const uint4*)(w_hh_bf + j * 512);
        for (int i = 0; i < 8; ++i)
            *(uint4*)&Bw[row][(seg + 8 * i) * 8] = src[seg + 8 * i];
    }
    // stage h0 (broadcast over batch)
    for (int i = 0; i < 8; ++i) {
        int col = (seg + 8 * i) * 8;
        float4 f0 = *(const float4*)(init_h + col);
        float4 f1 = *(const float4*)(init_h + col + 4);
        uint4 p;
        p.x = pack2(f0.x, f0.y);
        p.y = pack2(f0.z, f0.w);
        p.z = pack2(f1.x, f1.y);
        p.w = pack2(f1.z, f1.w);
        *(uint4*)&Ah[row][col] = p;
    }
    float c = init_c[k0 + seg];
    // prefetch xw[t=0]
    float xcur0, xcur1, xcur2, xcur3;
    {
        const float* p = xw + (row << 5) * 2048 + k0 + seg;
        xcur0 = p[0]; xcur1 = p[512]; xcur2 = p[1024]; xcur3 = p[1536];
    }
    __syncthreads();
    for (int t = 0; t < 32; ++t) {
        f32x4 acc = {};
#pragma unroll
        for (int kc = 0; kc < 16; ++kc) {
            bf16x8 a = *(const bf16x8*)&Ah[mi * 16 + l15][kc * 32 + quad * 8];
            bf16x8 b = *(const bf16x8*)&Bw[ni * 16 + l15][kc * 32 + quad * 8];
            acc = __builtin_amdgcn_mfma_f32_16x16x32_bf16(a, b, acc, 0, 0, 0);
        }
        {
            int r0 = mi * 16 + quad * 4, col = ni * 16 + l15;
            for (int r = 0; r < 4; ++r) gl[r0 + r][col] = acc[r];
        }
        __syncthreads();  // #1: gl ready; all Ah reads for step t complete
        int b = row, kg = k0 + seg;
        float gi = gl[b][seg] + xcur0;
        float gf = gl[b][8 + seg] + xcur1;
        float gg = gl[b][16 + seg] + xcur2;
        float go = gl[b][24 + seg] + xcur3;
        float cnew = fast_sig(gf) * c + fast_sig(gi) * fast_tanh(gg);
        c = cnew;
        float h = fast_sig(go) * fast_tanh(cnew);
        u16 hb = f2b(h);
        query[((b << 5) + t) * 512 + kg] = hb;
        if (t == 31) break;
        unsigned int tag = (unsigned int)(t + 1);
        // publish: per-thread tagged store (no gather, no ack, no flag)
        u32* dstbuf = hbuf32 + (t & 1) * 16384;
        __hip_atomic_store(&dstbuf[blockIdx.x * 256 + tid], (tag << 16) | (u32)hb,
                           __ATOMIC_RELAXED, __HIP_MEMORY_SCOPE_AGENT);
        // xw[t+1] prefetch (latency hides under the poll)
        float xn0, xn1, xn2, xn3;
        {
            const float* p = xw + ((row << 5) + (t + 1)) * 2048 + k0 + seg;
            xn0 = p[0]; xn1 = p[512]; xn2 = p[1024]; xn3 = p[1536];
        }
        // poll + restage: thread reads slot `tid` of all 64 src regions
        // (slot tid of src i  ==  h[row=tid>>3][col=i*8+seg], coalesced in i)
        {
            const u32* src = hbuf32 + (t & 1) * 16384;
            u32 vals[64];
#pragma unroll
            for (int i = 0; i < 64; ++i)
                vals[i] = __hip_atomic_load(&src[i * 256 + tid], __ATOMIC_RELAXED,
                                            __HIP_MEMORY_SCOPE_AGENT);
            for (;;) {
                u32 bad = 0;
#pragma unroll
                for (int i = 0; i < 64; ++i) bad |= ((vals[i] >> 16) ^ tag);
                if (bad == 0) break;
#pragma unroll
                for (int i = 0; i < 64; ++i)
                    if ((vals[i] >> 16) != tag)
                        vals[i] = __hip_atomic_load(&src[i * 256 + tid], __ATOMIC_RELAXED,
                                                    __HIP_MEMORY_SCOPE_AGENT);
            }
#pragma unroll
            for (int i = 0; i < 64; ++i) Ah[row][i * 8 + seg] = (u16)vals[i];
        }
        __syncthreads();  // #2: Ah(t+1) ready
        xcur0 = xn0; xcur1 = xn1; xcur2 = xn2; xcur3 = xn3;
    }
}

// ---------------- fused hop attention --------------------------------------
__launch_bounds__(256)
__global__ void k_hop(const u16* __restrict__ feat, const float* __restrict__ q,
                      const float* __restrict__ v, const int* __restrict__ mem_sizes,
                      u16* __restrict__ nq) {
    __shared__ float qs[512];
    __shared__ float vs[512];
    __shared__ float sc[128];
    __shared__ float ns[128];
    int bt = blockIdx.x;
    int b = bt >> 5;
    int tid = threadIdx.x;
    qs[tid] = q[bt * 512 + tid];
    qs[tid + 256] = q[bt * 512 + 256 + tid];
    vs[tid] = v[tid];
    vs[tid + 256] = v[tid + 256];
    __syncthreads();
    int lane = tid & 63, w = tid >> 6;
    int h0 = lane * 8;
    float qv[8], vv[8];
#pragma unroll
    for (int i = 0; i < 8; ++i) { qv[i] = qs[h0 + i]; vv[i] = vs[h0 + i]; }
    const u16* fb = feat + (size_t)b * 128 * 512;
    for (int i = 0; i < 32; ++i) {
        int n = w * 32 + i;
        uint4 fv = *(const uint4*)(fb + n * 512 + h0);
        float fr[8];
        fr[0] = b2f((u16)(fv.x & 0xFFFF)); fr[1] = b2f((u16)(fv.x >> 16));
        fr[2] = b2f((u16)(fv.y & 0xFFFF)); fr[3] = b2f((u16)(fv.y >> 16));
        fr[4] = b2f((u16)(fv.z & 0xFFFF)); fr[5] = b2f((u16)(fv.z >> 16));
        fr[6] = b2f((u16)(fv.w & 0xFFFF)); fr[7] = b2f((u16)(fv.w >> 16));
        float a = 0.f;
#pragma unroll
        for (int jj = 0; jj < 8; ++jj) a += fast_tanh(fr[jj] + qv[jj]) * vv[jj];
        for (int off = 1; off < 64; off <<= 1) a += __shfl_xor(a, off);
        if (lane == 0) sc[n] = a;
    }
    __syncthreads();
    if (tid < 64) {
        int ms = mem_sizes[b];
        float s0 = (tid < ms) ? sc[tid] : -1e30f;
        float s1 = (tid + 64 < ms) ? sc[tid + 64] : -1e30f;
        float m = fmaxf(s0, s1);
        for (int off = 1; off < 64; off <<= 1) m = fmaxf(m, __shfl_xor(m, off));
        float e0 = __expf(s0 - m), e1 = __expf(s1 - m);
        float s = e0 + e1;
        for (int off = 1; off < 64; off <<= 1) s += __shfl_xor(s, off);
        float r = fast_rcp(s);
        ns[tid] = e0 * r;
        ns[tid + 64] = e1 * r;
    }
    __syncthreads();
    float a0 = 0.f, a1 = 0.f;
    int hc = tid * 2;
    for (int n = 0; n < 128; ++n) {
        float f = ns[n];
        unsigned int pv = *(const unsigned int*)(fb + n * 512 + hc);
        a0 += f * b2f((u16)(pv & 0xFFFF));
        a1 += f * b2f((u16)(pv >> 16));
    }
    ((unsigned int*)nq)[bt * 256 + tid] = pack2(a0, a1);
}

// ---------------- final scores -> out (f32) --------------------------------
__launch_bounds__(256)
__global__ void k_score(const u16* __restrict__ feat, const float* __restrict__ q,
                        const float* __restrict__ v, float* __restrict__ outp) {
    __shared__ float qs[512];
    __shared__ float vs[512];
    __shared__ float sc[128];
    int bt = blockIdx.x;
    int b = bt >> 5;
    int tid = threadIdx.x;
    qs[tid] = q[bt * 512 + tid];
    qs[tid + 256] = q[bt * 512 + 256 + tid];
    vs[tid] = v[tid];
    vs[tid + 256] = v[tid + 256];
    __syncthreads();
    int lane = tid & 63, w = tid >> 6;
    int h0 = lane * 8;
    float qv[8], vv[8];
#pragma unroll
    for (int i = 0; i < 8; ++i) { qv[i] = qs[h0 + i]; vv[i] = vs[h0 + i]; }
    const u16* fb = feat + (size_t)b * 128 * 512;
    for (int i = 0; i < 32; ++i) {
        int n = w * 32 + i;
        uint4 fv = *(const uint4*)(fb + n * 512 + h0);
        float fr[8];
        fr[0] = b2f((u16)(fv.x & 0xFFFF)); fr[1] = b2f((u16)(fv.x >> 16));
        fr[2] = b2f((u16)(fv.y & 0xFFFF)); fr[3] = b2f((u16)(fv.y >> 16));
        fr[4] = b2f((u16)(fv.z & 0xFFFF)); fr[5] = b2f((u16)(fv.z >> 16));
        fr[6] = b2f((u16)(fv.w & 0xFFFF)); fr[7] = b2f((u16)(fv.w >> 16));
        float a = 0.f;
#pragma unroll
        for (int jj = 0; jj < 8; ++jj) a += fast_tanh(fr[jj] + qv[jj]) * vv[jj];
        for (int off = 1; off < 64; off <<= 1) a += __shfl_xor(a, off);
        if (lane == 0) sc[n] = a;
    }
    __syncthreads();
    if (tid < 128) outp[bt * 128 + tid] = sc[tid];
}

extern "C" void kernel_launch(void* const* d_in, const int* in_sizes, int n_in,
                              void* d_out, int out_size, void* d_ws, size_t ws_size,
                              hipStream_t stream) {
    (void)in_sizes; (void)n_in; (void)out_size; (void)ws_size;
    const float* attn_mem = (const float*)d_in[0];
    const int* mem_sizes = (const int*)d_in[1];
    const float* lstm_in = (const float*)d_in[2];
    const float* init_h = (const float*)d_in[3];
    const float* init_c = (const float*)d_in[4];
    const float* init_i = (const float*)d_in[5];
    const float* w_ih = (const float*)d_in[6];
    const float* w_hh = (const float*)d_in[7];
    const float* b_ih = (const float*)d_in[8];
    const float* b_hh = (const float*)d_in[9];
    const float* attn_wm = (const float*)d_in[10];
    const float* attn_wq = (const float*)d_in[11];
    const float* attn_v = (const float*)d_in[12];
    const float* hop_wm = (const float*)d_in[13];
    const float* hop_wq = (const float*)d_in[14];
    const float* hop_v = (const float*)d_in[15];
    float* out = (float*)d_out;

    char* ws = (char*)d_ws;
    size_t off = 0;
    auto alloc = [&](size_t bytes) {
        void* p = ws + off;
        off += (bytes + 255) & ~(size_t)255;
        return p;
    };
    u16* amem_bf = (u16*)alloc(4096 * 512 * 2);
    u16* xfull_bf = (u16*)alloc(1024 * 512 * 2);
    u16* wih_bf = (u16*)alloc(2048 * 512 * 2);
    u16* whh_bf = (u16*)alloc(2048 * 512 * 2);
    u16* WmT_hop = (u16*)alloc(512 * 512 * 2);
    u16* WmT_attn = (u16*)alloc(512 * 512 * 2);
    u16* WqT_hop = (u16*)alloc(512 * 512 * 2);
    u16* WqT_attn = (u16*)alloc(512 * 512 * 2);
    float* xw = (float*)alloc(1024 * 2048 * 4);
    u16* hop_feat = (u16*)alloc(4096 * 512 * 2);
    u16* attn_feat = (u16*)alloc(4096 * 512 * 2);
    u16* query = (u16*)alloc(1024 * 512 * 2);
    u32* hbuf32 = (u32*)alloc(2 * 64 * 256 * 4);  // [2][64 src][256] tagged u32
    float* qbuf = (float*)alloc(1024 * 512 * 4);
    u16* nq = (u16*)alloc(1024 * 512 * 2);

    k_prep<<<5632, 256, 0, stream>>>(attn_mem, amem_bf, w_ih, wih_bf, w_hh, whh_bf,
                                     lstm_in, init_i, xfull_bf,
                                     attn_wm, hop_wm, hop_wq, attn_wq,
                                     WmT_attn, WmT_hop, WqT_hop, WqT_attn);
    k_gemm<false><<<dim3(32, 16), 256, 0, stream>>>(xfull_bf, wih_bf, xw, 2048, b_ih, b_hh);
    k_feat<<<dim3(8, 128), 256, 0, stream>>>(amem_bf, WmT_hop, WmT_attn, hop_feat, attn_feat);
    k_lstm3<<<64, 256, 0, stream>>>(whh_bf, xw, init_h, init_c, query, hbuf32);
    k_gemm<false><<<dim3(8, 16), 256, 0, stream>>>(query, WqT_hop, qbuf, 512, nullptr, nullptr);
    k_hop<<<1024, 256, 0, stream>>>(hop_feat, qbuf, hop_v, mem_sizes, nq);
    k_gemm<false><<<dim3(8, 16), 256, 0, stream>>>(nq, WqT_attn, qbuf, 512, nullptr, nullptr);
    k_score<<<1024, 256, 0, stream>>>(attn_feat, qbuf, attn_v, out);
}

// Round 9
// 332.523 us; speedup vs baseline: 1.0949x; 1.0949x over previous
//
#include <hip/hip_runtime.h>

typedef unsigned short u16;
typedef unsigned int u32;
typedef unsigned long long u64;
typedef __bf16 bf16x8 __attribute__((ext_vector_type(8)));
typedef float f32x4 __attribute__((ext_vector_type(4)));

__device__ __forceinline__ float b2f(u16 u) {
    unsigned int x = ((unsigned int)u) << 16;
    return __builtin_bit_cast(float, x);
}
__device__ __forceinline__ u16 f2b(float f) {
    unsigned int u = __builtin_bit_cast(unsigned int, f);
    unsigned int r = (u + 0x7FFFu + ((u >> 16) & 1u)) >> 16;
    return (u16)r;
}
__device__ __forceinline__ unsigned int pack2(float a, float b) {
    return (unsigned int)f2b(a) | ((unsigned int)f2b(b) << 16);
}
__device__ __forceinline__ float fast_rcp(float x) { return __builtin_amdgcn_rcpf(x); }
__device__ __forceinline__ float fast_tanh(float x) {
    float e = __expf(2.f * x);
    return 1.f - 2.f * fast_rcp(e + 1.f);
}
__device__ __forceinline__ float fast_sig(float x) {
    float e = __expf(-x);
    return fast_rcp(1.f + e);
}

#define FLAG_STRIDE 32  // one flag per 128-B line

// ---------------- fused prep: casts + xfull + 4x transpose + flag zero ------
__launch_bounds__(256)
__global__ void k_prep(const float* __restrict__ attn_mem, u16* __restrict__ amem_bf,
                       const float* __restrict__ w_ih, u16* __restrict__ wih_bf,
                       const float* __restrict__ w_hh, u16* __restrict__ whh_bf,
                       const float* __restrict__ lstm_in, const float* __restrict__ init_i,
                       u16* __restrict__ xfull,
                       const float* s0, const float* s1, const float* s2, const float* s3,
                       u16* d0, u16* d1, u16* d2, u16* d3,
                       unsigned int* __restrict__ flags) {
    __shared__ float tile[32][33];
    int bid = blockIdx.x;
    int tid = threadIdx.x;
    if (bid == 0 && tid < 64)
        __hip_atomic_store(&flags[tid * FLAG_STRIDE], 0u, __ATOMIC_RELAXED,
                           __HIP_MEMORY_SCOPE_AGENT);
    if (bid < 4096) {
        const float* s;
        u16* d;
        int i;
        if (bid < 2048) { s = attn_mem; d = amem_bf; i = bid * 256 + tid; }
        else if (bid < 3072) { s = w_ih; d = wih_bf; i = (bid - 2048) * 256 + tid; }
        else { s = w_hh; d = whh_bf; i = (bid - 3072) * 256 + tid; }
        float4 a = ((const float4*)s)[i];
        uint2 p;
        p.x = pack2(a.x, a.y);
        p.y = pack2(a.z, a.w);
        ((uint2*)d)[i] = p;
    } else if (bid < 4608) {
        int idx = (bid - 4096) * 256 + tid;
        int c = idx & 127;
        int t = (idx >> 7) & 31;
        int b = idx >> 12;
        const float4* src = (t == 0) ? ((const float4*)init_i) + c
                                     : ((const float4*)lstm_in) + ((b * 31 + (t - 1)) * 128 + c);
        float4 a = *src;
        uint2 p;
        p.x = pack2(a.x, a.y);
        p.y = pack2(a.z, a.w);
        ((uint2*)xfull)[idx] = p;
    } else {
        int local = bid - 4608;
        int z = local >> 8, rem = local & 255;
        int by = (rem >> 4) * 32, bx = (rem & 15) * 32;
        const float* s;
        u16* d;
        switch (z) {
            case 0: s = s0; d = d0; break;
            case 1: s = s1; d = d1; break;
            case 2: s = s2; d = d2; break;
            default: s = s3; d = d3; break;
        }
        int tx = tid & 31, ty = tid >> 5;
        for (int i = 0; i < 32; i += 8) tile[ty + i][tx] = s[(by + ty + i) * 512 + bx + tx];
        __syncthreads();
        for (int i = 0; i < 32; i += 8) d[(bx + ty + i) * 512 + by + tx] = f2b(tile[tx][ty + i]);
    }
}

// ---------------- merged mid GEMMs: xw (512 blks) + hop/attn feat (1024) ---
__launch_bounds__(256)
__global__ void k_mid(const u16* __restrict__ xfull, const u16* __restrict__ wih,
                      float* __restrict__ xw,
                      const float* __restrict__ b_ih, const float* __restrict__ b_hh,
                      const u16* __restrict__ amem,
                      const u16* __restrict__ WmT_hop, const u16* __restrict__ WmT_attn,
                      u16* __restrict__ hop_feat, u16* __restrict__ attn_feat) {
    __shared__ u16 As[64][40];
    __shared__ u16 Bs[64][40];
    int id = blockIdx.x;
    const u16 *A, *Bt;
    float* Cf = nullptr;
    u16* Cb = nullptr;
    const float *bias1 = nullptr, *bias2 = nullptr;
    int m0, n0, GN;
    if (id < 512) {
        A = xfull; Bt = wih; GN = 2048;
        m0 = (id >> 5) * 64; n0 = (id & 31) * 64;
        Cf = xw; bias1 = b_ih; bias2 = b_hh;
    } else {
        int local = id - 512;
        A = amem; GN = 512;
        if (local < 512) { Bt = WmT_hop; Cb = hop_feat; }
        else { Bt = WmT_attn; Cb = attn_feat; local -= 512; }
        m0 = (local >> 3) * 64; n0 = (local & 7) * 64;
    }
    int tid = threadIdx.x;
    int lane = tid & 63, w = tid >> 6;
    int wm = w >> 1, wn = w & 1;
    int l15 = lane & 15, quad = lane >> 4;
    f32x4 acc[2][2] = {};
    int ar = tid >> 2, ac = (tid & 3) * 8;
    const u16* Ap = A + (m0 + ar) * 512 + ac;
    const u16* Bp = Bt + (n0 + ar) * 512 + ac;
    for (int kt = 0; kt < 16; ++kt) {
        uint4 av = *(const uint4*)(Ap + kt * 32);
        uint4 bv = *(const uint4*)(Bp + kt * 32);
        __syncthreads();
        *(uint4*)&As[ar][ac] = av;
        *(uint4*)&Bs[ar][ac] = bv;
        __syncthreads();
        bf16x8 a0 = *(const bf16x8*)&As[wm * 32 + l15][quad * 8];
        bf16x8 a1 = *(const bf16x8*)&As[wm * 32 + 16 + l15][quad * 8];
        bf16x8 b0 = *(const bf16x8*)&Bs[wn * 32 + l15][quad * 8];
        bf16x8 b1 = *(const bf16x8*)&Bs[wn * 32 + 16 + l15][quad * 8];
        acc[0][0] = __builtin_amdgcn_mfma_f32_16x16x32_bf16(a0, b0, acc[0][0], 0, 0, 0);
        acc[0][1] = __builtin_amdgcn_mfma_f32_16x16x32_bf16(a0, b1, acc[0][1], 0, 0, 0);
        acc[1][0] = __builtin_amdgcn_mfma_f32_16x16x32_bf16(a1, b0, acc[1][0], 0, 0, 0);
        acc[1][1] = __builtin_amdgcn_mfma_f32_16x16x32_bf16(a1, b1, acc[1][1], 0, 0, 0);
    }
    for (int ai = 0; ai < 2; ++ai)
        for (int bi = 0; bi < 2; ++bi) {
            int row = m0 + wm * 32 + ai * 16 + quad * 4;
            int col = n0 + wn * 32 + bi * 16 + l15;
            if (Cb) {
                for (int r = 0; r < 4; ++r) Cb[(row + r) * GN + col] = f2b(acc[ai][bi][r]);
            } else {
                float bias = bias1[col] + bias2[col];
                for (int r = 0; r < 4; ++r) Cf[(row + r) * GN + col] = acc[ai][bi][r] + bias;
            }
        }
}

// ---------------- standalone GEMM (K=512) for nq @ WqT_attn ----------------
template <bool BF16OUT>
__launch_bounds__(256)
__global__ void k_gemm(const u16* __restrict__ A, const u16* __restrict__ Bt,
                       void* __restrict__ Cv, int GN,
                       const float* __restrict__ bias1, const float* __restrict__ bias2) {
    __shared__ u16 As[64][40];
    __shared__ u16 Bs[64][40];
    int m0 = blockIdx.y * 64, n0 = blockIdx.x * 64;
    int tid = threadIdx.x;
    int lane = tid & 63, w = tid >> 6;
    int wm = w >> 1, wn = w & 1;
    int l15 = lane & 15, quad = lane >> 4;
    f32x4 acc[2][2] = {};
    int ar = tid >> 2, ac = (tid & 3) * 8;
    const u16* Ap = A + (m0 + ar) * 512 + ac;
    const u16* Bp = Bt + (n0 + ar) * 512 + ac;
    for (int kt = 0; kt < 16; ++kt) {
        uint4 av = *(const uint4*)(Ap + kt * 32);
        uint4 bv = *(const uint4*)(Bp + kt * 32);
        __syncthreads();
        *(uint4*)&As[ar][ac] = av;
        *(uint4*)&Bs[ar][ac] = bv;
        __syncthreads();
        bf16x8 a0 = *(const bf16x8*)&As[wm * 32 + l15][quad * 8];
        bf16x8 a1 = *(const bf16x8*)&As[wm * 32 + 16 + l15][quad * 8];
        bf16x8 b0 = *(const bf16x8*)&Bs[wn * 32 + l15][quad * 8];
        bf16x8 b1 = *(const bf16x8*)&Bs[wn * 32 + 16 + l15][quad * 8];
        acc[0][0] = __builtin_amdgcn_mfma_f32_16x16x32_bf16(a0, b0, acc[0][0], 0, 0, 0);
        acc[0][1] = __builtin_amdgcn_mfma_f32_16x16x32_bf16(a0, b1, acc[0][1], 0, 0, 0);
        acc[1][0] = __builtin_amdgcn_mfma_f32_16x16x32_bf16(a1, b0, acc[1][0], 0, 0, 0);
        acc[1][1] = __builtin_amdgcn_mfma_f32_16x16x32_bf16(a1, b1, acc[1][1], 0, 0, 0);
    }
    for (int ai = 0; ai < 2; ++ai)
        for (int bi = 0; bi < 2; ++bi) {
            int row = m0 + wm * 32 + ai * 16 + quad * 4;
            int col = n0 + wn * 32 + bi * 16 + l15;
            float bias = 0.f;
            if (bias1) bias = bias1[col] + bias2[col];
            if constexpr (BF16OUT) {
                u16* C = (u16*)Cv;
                for (int r = 0; r < 4; ++r) C[(row + r) * GN + col] = f2b(acc[ai][bi][r] + bias);
            } else {
                float* C = (float*)Cv;
                for (int r = 0; r < 4; ++r) C[(row + r) * GN + col] = acc[ai][bi][r] + bias;
            }
        }
}

// ---------------- persistent LSTM (r7 sync core) + embedded q2 GEMM --------
// 64 blocks x 256. Block owns k-cols [bid*8,bid*8+8) of all 4 gates.
// While wave 0 polls flags, waves 1-2 compute the block's 8 columns of
// q2 = query @ WqT_hop for time index t-1 (full h(t) is in LDS).
// 32 exchanges (incl. t=31) so h(32)=query[31] is available for the epilogue.
__launch_bounds__(256, 1)
__global__ void k_lstm4(const u16* __restrict__ w_hh_bf, const float* __restrict__ xw,
                        const float* __restrict__ init_h, const float* __restrict__ init_c,
                        const u16* __restrict__ wq_hop_T, float* __restrict__ qbuf,
                        u64* __restrict__ hbuf, unsigned int* __restrict__ flags) {
    __shared__ u16 Bw[32][520];
    __shared__ u16 Ah[32][520];
    __shared__ float gl[32][33];
    __shared__ u16 gbuf[32][8];
    __shared__ u16 Wq[16][520];  // rows 0..7 = WqT_hop rows k0..k0+7; rows 8..15 zero
    int tid = threadIdx.x;
    int k0 = blockIdx.x * 8;
    int lane = tid & 63, w = tid >> 6;
    int mi = w >> 1, ni = w & 1;
    int l15 = lane & 15, quad = lane >> 4;
    int row = tid >> 3, seg = tid & 7;
    // stage w_hh slice (local col r <-> w_hh row (r>>3)*512 + k0 + (r&7))
    {
        int j = (row >> 3) * 512 + k0 + (row & 7);
        const uint4* src = (const uint4*)(w_hh_bf + j * 512);
        for (int i = 0; i < 8; ++i)
            *(uint4*)&Bw[row][(seg + 8 * i) * 8] = src[seg + 8 * i];
    }
    // stage Wq slice: rows 0..7 data, rows 8..15 zero
    if (row < 16) {
        if (row < 8) {
            const uint4* src = (const uint4*)(wq_hop_T + (k0 + row) * 512);
            for (int i = 0; i < 8; ++i)
                *(uint4*)&Wq[row][(seg + 8 * i) * 8] = src[seg + 8 * i];
        } else {
            uint4 z = {0, 0, 0, 0};
            for (int i = 0; i < 8; ++i)
                *(uint4*)&Wq[row][(seg + 8 * i) * 8] = z;
        }
    }
    // stage h0 (broadcast over batch)
    for (int i = 0; i < 8; ++i) {
        int col = (seg + 8 * i) * 8;
        float4 f0 = *(const float4*)(init_h + col);
        float4 f1 = *(const float4*)(init_h + col + 4);
        uint4 p;
        p.x = pack2(f0.x, f0.y);
        p.y = pack2(f0.z, f0.w);
        p.z = pack2(f1.x, f1.y);
        p.w = pack2(f1.z, f1.w);
        *(uint4*)&Ah[row][col] = p;
    }
    float c = init_c[k0 + seg];
    // prefetch xw[t=0]
    float xcur0, xcur1, xcur2, xcur3;
    {
        const float* p = xw + (row << 5) * 2048 + k0 + seg;
        xcur0 = p[0]; xcur1 = p[512]; xcur2 = p[1024]; xcur3 = p[1536];
    }
    __syncthreads();
    for (int t = 0; t < 32; ++t) {
        f32x4 acc = {};
#pragma unroll
        for (int kc = 0; kc < 16; ++kc) {
            bf16x8 a = *(const bf16x8*)&Ah[mi * 16 + l15][kc * 32 + quad * 8];
            bf16x8 b = *(const bf16x8*)&Bw[ni * 16 + l15][kc * 32 + quad * 8];
            acc = __builtin_amdgcn_mfma_f32_16x16x32_bf16(a, b, acc, 0, 0, 0);
        }
        {
            int r0 = mi * 16 + quad * 4, col = ni * 16 + l15;
            for (int r = 0; r < 4; ++r) gl[r0 + r][col] = acc[r];
        }
        __syncthreads();  // #1
        int b = row, kg = k0 + seg;
        float gi = gl[b][seg] + xcur0;
        float gf = gl[b][8 + seg] + xcur1;
        float gg = gl[b][16 + seg] + xcur2;
        float go = gl[b][24 + seg] + xcur3;
        float cnew = fast_sig(gf) * c + fast_sig(gi) * fast_tanh(gg);
        c = cnew;
        float h = fast_sig(go) * fast_tanh(cnew);
        u16 hb = f2b(h);
        gbuf[b][seg] = hb;
        __syncthreads();  // #2
        if (tid < 64) {
            // wave 0: publish block's h slice (line-private burst) + flag + poll
            int b2 = tid >> 1, half = tid & 1;
            u64 v = *(const u64*)&gbuf[b2][half * 4];
            u64* dst = hbuf + (t & 1) * 4096 + blockIdx.x * 64 + tid;
            __hip_atomic_store(dst, v, __ATOMIC_RELAXED, __HIP_MEMORY_SCOPE_AGENT);
            __builtin_amdgcn_s_waitcnt(0);
            if (tid == 0)
                __hip_atomic_store(&flags[blockIdx.x * FLAG_STRIDE], (unsigned int)(t + 1),
                                   __ATOMIC_RELAXED, __HIP_MEMORY_SCOPE_AGENT);
            while (true) {
                unsigned int f = __hip_atomic_load(&flags[tid * FLAG_STRIDE],
                                                   __ATOMIC_RELAXED, __HIP_MEMORY_SCOPE_AGENT);
                if (__ballot(f > (unsigned int)t) == ~0ull) break;
                __builtin_amdgcn_s_sleep(1);
            }
        } else if (t > 0 && w <= 2) {
            // waves 1-2: q2 slice for time index t-1 (Ah = h(t) = query[t-1])
            int mt = w - 1;
            f32x4 acc2 = {};
#pragma unroll
            for (int kc = 0; kc < 16; ++kc) {
                bf16x8 a = *(const bf16x8*)&Ah[mt * 16 + l15][kc * 32 + quad * 8];
                bf16x8 bq = *(const bf16x8*)&Wq[l15][kc * 32 + quad * 8];
                acc2 = __builtin_amdgcn_mfma_f32_16x16x32_bf16(a, bq, acc2, 0, 0, 0);
            }
            if (l15 < 8) {
                int bidx = mt * 16 + quad * 4;
                for (int r = 0; r < 4; ++r)
                    qbuf[(((bidx + r) << 5) + (t - 1)) * 512 + k0 + l15] = acc2[r];
            }
        }
        __syncthreads();  // #3
        // overlapped phase: restage h(t+1) + xw prefetch
        int tn = (t < 31) ? t + 1 : 31;
        float xn0, xn1, xn2, xn3;
        {
            const float* p = xw + ((row << 5) + tn) * 2048 + k0 + seg;
            xn0 = p[0]; xn1 = p[512]; xn2 = p[1024]; xn3 = p[1536];
        }
        {
            const u64* src = hbuf + (t & 1) * 4096;
#pragma unroll
            for (int i = 0; i < 8; ++i) {
                int bid2 = seg + 8 * i;
                u64 v0 = __hip_atomic_load(&src[bid2 * 64 + row * 2], __ATOMIC_RELAXED,
                                           __HIP_MEMORY_SCOPE_AGENT);
                u64 v1 = __hip_atomic_load(&src[bid2 * 64 + row * 2 + 1], __ATOMIC_RELAXED,
                                           __HIP_MEMORY_SCOPE_AGENT);
                *(u64*)&Ah[row][bid2 * 8] = v0;
                *(u64*)&Ah[row][bid2 * 8 + 4] = v1;
            }
        }
        __syncthreads();  // #4
        xcur0 = xn0; xcur1 = xn1; xcur2 = xn2; xcur3 = xn3;
    }
    // epilogue: q2 slice for time index 31 (Ah = h(32) = query[31])
    if (w == 1 || w == 2) {
        int mt = w - 1;
        f32x4 acc2 = {};
#pragma unroll
        for (int kc = 0; kc < 16; ++kc) {
            bf16x8 a = *(const bf16x8*)&Ah[mt * 16 + l15][kc * 32 + quad * 8];
            bf16x8 bq = *(const bf16x8*)&Wq[l15][kc * 32 + quad * 8];
            acc2 = __builtin_amdgcn_mfma_f32_16x16x32_bf16(a, bq, acc2, 0, 0, 0);
        }
        if (l15 < 8) {
            int bidx = mt * 16 + quad * 4;
            for (int r = 0; r < 4; ++r)
                qbuf[(((bidx + r) << 5) + 31) * 512 + k0 + l15] = acc2[r];
        }
    }
}

// ---------------- fused hop attention --------------------------------------
__launch_bounds__(256)
__global__ void k_hop(const u16* __restrict__ feat, const float* __restrict__ q,
                      const float* __restrict__ v, const int* __restrict__ mem_sizes,
                      u16* __restrict__ nq) {
    __shared__ float qs[512];
    __shared__ float vs[512];
    __shared__ float sc[128];
    __shared__ float ns[128];
    int bt = blockIdx.x;
    int b = bt >> 5;
    int tid = threadIdx.x;
    qs[tid] = q[bt * 512 + tid];
    qs[tid + 256] = q[bt * 512 + 256 + tid];
    vs[tid] = v[tid];
    vs[tid + 256] = v[tid + 256];
    __syncthreads();
    int lane = tid & 63, w = tid >> 6;
    int h0 = lane * 8;
    float qv[8], vv[8];
#pragma unroll
    for (int i = 0; i < 8; ++i) { qv[i] = qs[h0 + i]; vv[i] = vs[h0 + i]; }
    const u16* fb = feat + (size_t)b * 128 * 512;
    for (int i = 0; i < 32; ++i) {
        int n = w * 32 + i;
        uint4 fv = *(const uint4*)(fb + n * 512 + h0);
        float fr[8];
        fr[0] = b2f((u16)(fv.x & 0xFFFF)); fr[1] = b2f((u16)(fv.x >> 16));
        fr[2] = b2f((u16)(fv.y & 0xFFFF)); fr[3] = b2f((u16)(fv.y >> 16));
        fr[4] = b2f((u16)(fv.z & 0xFFFF)); fr[5] = b2f((u16)(fv.z >> 16));
        fr[6] = b2f((u16)(fv.w & 0xFFFF)); fr[7] = b2f((u16)(fv.w >> 16));
        float a = 0.f;
#pragma unroll
        for (int jj = 0; jj < 8; ++jj) a += fast_tanh(fr[jj] + qv[jj]) * vv[jj];
        for (int off = 1; off < 64; off <<= 1) a += __shfl_xor(a, off);
        if (lane == 0) sc[n] = a;
    }
    __syncthreads();
    if (tid < 64) {
        int ms = mem_sizes[b];
        float s0 = (tid < ms) ? sc[tid] : -1e30f;
        float s1 = (tid + 64 < ms) ? sc[tid + 64] : -1e30f;
        float m = fmaxf(s0, s1);
        for (int off = 1; off < 64; off <<= 1) m = fmaxf(m, __shfl_xor(m, off));
        float e0 = __expf(s0 - m), e1 = __expf(s1 - m);
        float s = e0 + e1;
        for (int off = 1; off < 64; off <<= 1) s += __shfl_xor(s, off);
        float r = fast_rcp(s);
        ns[tid] = e0 * r;
        ns[tid + 64] = e1 * r;
    }
    __syncthreads();
    float a0 = 0.f, a1 = 0.f;
    int hc = tid * 2;
    for (int n = 0; n < 128; ++n) {
        float f = ns[n];
        unsigned int pv = *(const unsigned int*)(fb + n * 512 + hc);
        a0 += f * b2f((u16)(pv & 0xFFFF));
        a1 += f * b2f((u16)(pv >> 16));
    }
    ((unsigned int*)nq)[bt * 256 + tid] = pack2(a0, a1);
}

// ---------------- final scores -> out (f32) --------------------------------
__launch_bounds__(256)
__global__ void k_score(const u16* __restrict__ feat, const float* __restrict__ q,
                        const float* __restrict__ v, float* __restrict__ outp) {
    __shared__ float qs[512];
    __shared__ float vs[512];
    __shared__ float sc[128];
    int bt = blockIdx.x;
    int b = bt >> 5;
    int tid = threadIdx.x;
    qs[tid] = q[bt * 512 + tid];
    qs[tid + 256] = q[bt * 512 + 256 + tid];
    vs[tid] = v[tid];
    vs[tid + 256] = v[tid + 256];
    __syncthreads();
    int lane = tid & 63, w = tid >> 6;
    int h0 = lane * 8;
    float qv[8], vv[8];
#pragma unroll
    for (int i = 0; i < 8; ++i) { qv[i] = qs[h0 + i]; vv[i] = vs[h0 + i]; }
    const u16* fb = feat + (size_t)b * 128 * 512;
    for (int i = 0; i < 32; ++i) {
        int n = w * 32 + i;
        uint4 fv = *(const uint4*)(fb + n * 512 + h0);
        float fr[8];
        fr[0] = b2f((u16)(fv.x & 0xFFFF)); fr[1] = b2f((u16)(fv.x >> 16));
        fr[2] = b2f((u16)(fv.y & 0xFFFF)); fr[3] = b2f((u16)(fv.y >> 16));
        fr[4] = b2f((u16)(fv.z & 0xFFFF)); fr[5] = b2f((u16)(fv.z >> 16));
        fr[6] = b2f((u16)(fv.w & 0xFFFF)); fr[7] = b2f((u16)(fv.w >> 16));
        float a = 0.f;
#pragma unroll
        for (int jj = 0; jj < 8; ++jj) a += fast_tanh(fr[jj] + qv[jj]) * vv[jj];
        for (int off = 1; off < 64; off <<= 1) a += __shfl_xor(a, off);
        if (lane == 0) sc[n] = a;
    }
    __syncthreads();
    if (tid < 128) outp[bt * 128 + tid] = sc[tid];
}

extern "C" void kernel_launch(void* const* d_in, const int* in_sizes, int n_in,
                              void* d_out, int out_size, void* d_ws, size_t ws_size,
                              hipStream_t stream) {
    (void)in_sizes; (void)n_in; (void)out_size; (void)ws_size;
    const float* attn_mem = (const float*)d_in[0];
    const int* mem_sizes = (const int*)d_in[1];
    const float* lstm_in = (const float*)d_in[2];
    const float* init_h = (const float*)d_in[3];
    const float* init_c = (const float*)d_in[4];
    const float* init_i = (const float*)d_in[5];
    const float* w_ih = (const float*)d_in[6];
    const float* w_hh = (const float*)d_in[7];
    const float* b_ih = (const float*)d_in[8];
    const float* b_hh = (const float*)d_in[9];
    const float* attn_wm = (const float*)d_in[10];
    const float* attn_wq = (const float*)d_in[11];
    const float* attn_v = (const float*)d_in[12];
    const float* hop_wm = (const float*)d_in[13];
    const float* hop_wq = (const float*)d_in[14];
    const float* hop_v = (const float*)d_in[15];
    float* out = (float*)d_out;

    char* ws = (char*)d_ws;
    size_t off = 0;
    auto alloc = [&](size_t bytes) {
        void* p = ws + off;
        off += (bytes + 255) & ~(size_t)255;
        return p;
    };
    u16* amem_bf = (u16*)alloc(4096 * 512 * 2);
    u16* xfull_bf = (u16*)alloc(1024 * 512 * 2);
    u16* wih_bf = (u16*)alloc(2048 * 512 * 2);
    u16* whh_bf = (u16*)alloc(2048 * 512 * 2);
    u16* WmT_hop = (u16*)alloc(512 * 512 * 2);
    u16* WmT_attn = (u16*)alloc(512 * 512 * 2);
    u16* WqT_hop = (u16*)alloc(512 * 512 * 2);
    u16* WqT_attn = (u16*)alloc(512 * 512 * 2);
    float* xw = (float*)alloc(1024 * 2048 * 4);
    u16* hop_feat = (u16*)alloc(4096 * 512 * 2);
    u16* attn_feat = (u16*)alloc(4096 * 512 * 2);
    u64* hbuf = (u64*)alloc(2 * 64 * 64 * 8);                        // [2][64][64] u64
    unsigned int* flags = (unsigned int*)alloc(64 * FLAG_STRIDE * 4);  // 1 flag / 128B line
    float* qbuf = (float*)alloc(1024 * 512 * 4);
    u16* nq = (u16*)alloc(1024 * 512 * 2);

    k_prep<<<5632, 256, 0, stream>>>(attn_mem, amem_bf, w_ih, wih_bf, w_hh, whh_bf,
                                     lstm_in, init_i, xfull_bf,
                                     attn_wm, hop_wm, hop_wq, attn_wq,
                                     WmT_attn, WmT_hop, WqT_hop, WqT_attn, flags);
    k_mid<<<1536, 256, 0, stream>>>(xfull_bf, wih_bf, xw, b_ih, b_hh,
                                    amem_bf, WmT_hop, WmT_attn, hop_feat, attn_feat);
    k_lstm4<<<64, 256, 0, stream>>>(whh_bf, xw, init_h, init_c, WqT_hop, qbuf, hbuf, flags);
    k_hop<<<1024, 256, 0, stream>>>(hop_feat, qbuf, hop_v, mem_sizes, nq);
    k_gemm<false><<<dim3(8, 16), 256, 0, stream>>>(nq, WqT_attn, qbuf, 512, nullptr, nullptr);
    k_score<<<1024, 256, 0, stream>>>(attn_feat, qbuf, attn_v, out);
}

// Round 10
// 322.501 us; speedup vs baseline: 1.1290x; 1.0311x over previous
//
#include <hip/hip_runtime.h>

typedef unsigned short u16;
typedef unsigned int u32;
typedef unsigned long long u64;
typedef __bf16 bf16x8 __attribute__((ext_vector_type(8)));
typedef float f32x4 __attribute__((ext_vector_type(4)));

__device__ __forceinline__ float b2f(u16 u) {
    unsigned int x = ((unsigned int)u) << 16;
    return __builtin_bit_cast(float, x);
}
__device__ __forceinline__ u16 f2b(float f) {
    unsigned int u = __builtin_bit_cast(unsigned int, f);
    unsigned int r = (u + 0x7FFFu + ((u >> 16) & 1u)) >> 16;
    return (u16)r;
}
__device__ __forceinline__ unsigned int pack2(float a, float b) {
    return (unsigned int)f2b(a) | ((unsigned int)f2b(b) << 16);
}
__device__ __forceinline__ float fast_rcp(float x) { return __builtin_amdgcn_rcpf(x); }
__device__ __forceinline__ float fast_tanh(float x) {
    float e = __expf(2.f * x);
    return 1.f - 2.f * fast_rcp(e + 1.f);
}
__device__ __forceinline__ float fast_sig(float x) {
    float e = __expf(-x);
    return fast_rcp(1.f + e);
}

#define FLAG_STRIDE 32  // one flag per 128-B line

// ---------------- fused prep: casts + xfull + 4x transpose + flag zero ------
__launch_bounds__(256)
__global__ void k_prep(const float* __restrict__ attn_mem, u16* __restrict__ amem_bf,
                       const float* __restrict__ w_ih, u16* __restrict__ wih_bf,
                       const float* __restrict__ w_hh, u16* __restrict__ whh_bf,
                       const float* __restrict__ lstm_in, const float* __restrict__ init_i,
                       u16* __restrict__ xfull,
                       const float* s0, const float* s1, const float* s2, const float* s3,
                       u16* d0, u16* d1, u16* d2, u16* d3,
                       unsigned int* __restrict__ flags) {
    __shared__ float tile[32][33];
    int bid = blockIdx.x;
    int tid = threadIdx.x;
    if (bid == 0 && tid < 64)
        __hip_atomic_store(&flags[tid * FLAG_STRIDE], 0u, __ATOMIC_RELAXED,
                           __HIP_MEMORY_SCOPE_AGENT);
    if (bid < 4096) {
        const float* s;
        u16* d;
        int i;
        if (bid < 2048) { s = attn_mem; d = amem_bf; i = bid * 256 + tid; }
        else if (bid < 3072) { s = w_ih; d = wih_bf; i = (bid - 2048) * 256 + tid; }
        else { s = w_hh; d = whh_bf; i = (bid - 3072) * 256 + tid; }
        float4 a = ((const float4*)s)[i];
        uint2 p;
        p.x = pack2(a.x, a.y);
        p.y = pack2(a.z, a.w);
        ((uint2*)d)[i] = p;
    } else if (bid < 4608) {
        int idx = (bid - 4096) * 256 + tid;
        int c = idx & 127;
        int t = (idx >> 7) & 31;
        int b = idx >> 12;
        const float4* src = (t == 0) ? ((const float4*)init_i) + c
                                     : ((const float4*)lstm_in) + ((b * 31 + (t - 1)) * 128 + c);
        float4 a = *src;
        uint2 p;
        p.x = pack2(a.x, a.y);
        p.y = pack2(a.z, a.w);
        ((uint2*)xfull)[idx] = p;
    } else {
        int local = bid - 4608;
        int z = local >> 8, rem = local & 255;
        int by = (rem >> 4) * 32, bx = (rem & 15) * 32;
        const float* s;
        u16* d;
        switch (z) {
            case 0: s = s0; d = d0; break;
            case 1: s = s1; d = d1; break;
            case 2: s = s2; d = d2; break;
            default: s = s3; d = d3; break;
        }
        int tx = tid & 31, ty = tid >> 5;
        for (int i = 0; i < 32; i += 8) tile[ty + i][tx] = s[(by + ty + i) * 512 + bx + tx];
        __syncthreads();
        for (int i = 0; i < 32; i += 8) d[(bx + ty + i) * 512 + by + tx] = f2b(tile[tx][ty + i]);
    }
}

// ---------------- xw GEMM only: 512 blocks ---------------------------------
__launch_bounds__(256)
__global__ void k_xw(const u16* __restrict__ xfull, const u16* __restrict__ wih,
                     float* __restrict__ xw,
                     const float* __restrict__ b_ih, const float* __restrict__ b_hh) {
    __shared__ u16 As[64][40];
    __shared__ u16 Bs[64][40];
    int id = blockIdx.x;
    int m0 = (id >> 5) * 64, n0 = (id & 31) * 64;
    int tid = threadIdx.x;
    int lane = tid & 63, w = tid >> 6;
    int wm = w >> 1, wn = w & 1;
    int l15 = lane & 15, quad = lane >> 4;
    f32x4 acc[2][2] = {};
    int ar = tid >> 2, ac = (tid & 3) * 8;
    const u16* Ap = xfull + (m0 + ar) * 512 + ac;
    const u16* Bp = wih + (n0 + ar) * 512 + ac;
    for (int kt = 0; kt < 16; ++kt) {
        uint4 av = *(const uint4*)(Ap + kt * 32);
        uint4 bv = *(const uint4*)(Bp + kt * 32);
        __syncthreads();
        *(uint4*)&As[ar][ac] = av;
        *(uint4*)&Bs[ar][ac] = bv;
        __syncthreads();
        bf16x8 a0 = *(const bf16x8*)&As[wm * 32 + l15][quad * 8];
        bf16x8 a1 = *(const bf16x8*)&As[wm * 32 + 16 + l15][quad * 8];
        bf16x8 b0 = *(const bf16x8*)&Bs[wn * 32 + l15][quad * 8];
        bf16x8 b1 = *(const bf16x8*)&Bs[wn * 32 + 16 + l15][quad * 8];
        acc[0][0] = __builtin_amdgcn_mfma_f32_16x16x32_bf16(a0, b0, acc[0][0], 0, 0, 0);
        acc[0][1] = __builtin_amdgcn_mfma_f32_16x16x32_bf16(a0, b1, acc[0][1], 0, 0, 0);
        acc[1][0] = __builtin_amdgcn_mfma_f32_16x16x32_bf16(a1, b0, acc[1][0], 0, 0, 0);
        acc[1][1] = __builtin_amdgcn_mfma_f32_16x16x32_bf16(a1, b1, acc[1][1], 0, 0, 0);
    }
    for (int ai = 0; ai < 2; ++ai)
        for (int bi = 0; bi < 2; ++bi) {
            int row = m0 + wm * 32 + ai * 16 + quad * 4;
            int col = n0 + wn * 32 + bi * 16 + l15;
            float bias = b_ih[col] + b_hh[col];
            for (int r = 0; r < 4; ++r) xw[(row + r) * 2048 + col] = acc[ai][bi][r] + bias;
        }
}

// ---------------- standalone GEMM (K=512) for nq @ WqT_attn ----------------
__launch_bounds__(256)
__global__ void k_gemm(const u16* __restrict__ A, const u16* __restrict__ Bt,
                       float* __restrict__ C, int GN) {
    __shared__ u16 As[64][40];
    __shared__ u16 Bs[64][40];
    int m0 = blockIdx.y * 64, n0 = blockIdx.x * 64;
    int tid = threadIdx.x;
    int lane = tid & 63, w = tid >> 6;
    int wm = w >> 1, wn = w & 1;
    int l15 = lane & 15, quad = lane >> 4;
    f32x4 acc[2][2] = {};
    int ar = tid >> 2, ac = (tid & 3) * 8;
    const u16* Ap = A + (m0 + ar) * 512 + ac;
    const u16* Bp = Bt + (n0 + ar) * 512 + ac;
    for (int kt = 0; kt < 16; ++kt) {
        uint4 av = *(const uint4*)(Ap + kt * 32);
        uint4 bv = *(const uint4*)(Bp + kt * 32);
        __syncthreads();
        *(uint4*)&As[ar][ac] = av;
        *(uint4*)&Bs[ar][ac] = bv;
        __syncthreads();
        bf16x8 a0 = *(const bf16x8*)&As[wm * 32 + l15][quad * 8];
        bf16x8 a1 = *(const bf16x8*)&As[wm * 32 + 16 + l15][quad * 8];
        bf16x8 b0 = *(const bf16x8*)&Bs[wn * 32 + l15][quad * 8];
        bf16x8 b1 = *(const bf16x8*)&Bs[wn * 32 + 16 + l15][quad * 8];
        acc[0][0] = __builtin_amdgcn_mfma_f32_16x16x32_bf16(a0, b0, acc[0][0], 0, 0, 0);
        acc[0][1] = __builtin_amdgcn_mfma_f32_16x16x32_bf16(a0, b1, acc[0][1], 0, 0, 0);
        acc[1][0] = __builtin_amdgcn_mfma_f32_16x16x32_bf16(a1, b0, acc[1][0], 0, 0, 0);
        acc[1][1] = __builtin_amdgcn_mfma_f32_16x16x32_bf16(a1, b1, acc[1][1], 0, 0, 0);
    }
    for (int ai = 0; ai < 2; ++ai)
        for (int bi = 0; bi < 2; ++bi) {
            int row = m0 + wm * 32 + ai * 16 + quad * 4;
            int col = n0 + wn * 32 + bi * 16 + l15;
            for (int r = 0; r < 4; ++r) C[(row + r) * GN + col] = acc[ai][bi][r];
        }
}

// ---------------- persistent LSTM (r9 core) + shadowed feat GEMMs ----------
// blocks [0,64): LSTM, k-cols [bid*8,bid*8+8) of all 4 gates; embedded q2.
// blocks [64,1088): hop_feat / attn_feat GEMMs -- run on idle CUs under the
// LSTM's time shadow (r5 evidence: co-residency is free).
__launch_bounds__(256, 1)
__global__ void k_lstm5(const u16* __restrict__ w_hh_bf, const float* __restrict__ xw,
                        const float* __restrict__ init_h, const float* __restrict__ init_c,
                        const u16* __restrict__ wq_hop_T, float* __restrict__ qbuf,
                        u64* __restrict__ hbuf, unsigned int* __restrict__ flags,
                        const u16* __restrict__ amem_bf,
                        const u16* __restrict__ WmT_hop, const u16* __restrict__ WmT_attn,
                        u16* __restrict__ hop_feat, u16* __restrict__ attn_feat) {
    __shared__ u16 Bw[32][520];
    __shared__ u16 Ah[32][520];
    __shared__ float gl[32][33];
    __shared__ u16 gbuf[32][8];
    __shared__ u16 Wq[16][520];
    __shared__ u16 As[64][40];
    __shared__ u16 Bs[64][40];
    int tid = threadIdx.x;
    if (blockIdx.x >= 64) {
        // ---- feat GEMM tail ----
        int local = (int)blockIdx.x - 64;
        const u16* Bt;
        u16* C;
        if (local < 512) { Bt = WmT_hop; C = hop_feat; }
        else { Bt = WmT_attn; C = attn_feat; local -= 512; }
        int m0 = (local >> 3) * 64, n0 = (local & 7) * 64;
        int lane = tid & 63, w = tid >> 6;
        int wm = w >> 1, wn = w & 1;
        int l15 = lane & 15, quad = lane >> 4;
        f32x4 acc[2][2] = {};
        int ar = tid >> 2, ac = (tid & 3) * 8;
        const u16* Ap = amem_bf + (m0 + ar) * 512 + ac;
        const u16* Bp = Bt + (n0 + ar) * 512 + ac;
        for (int kt = 0; kt < 16; ++kt) {
            uint4 av = *(const uint4*)(Ap + kt * 32);
            uint4 bv = *(const uint4*)(Bp + kt * 32);
            __syncthreads();
            *(uint4*)&As[ar][ac] = av;
            *(uint4*)&Bs[ar][ac] = bv;
            __syncthreads();
            bf16x8 a0 = *(const bf16x8*)&As[wm * 32 + l15][quad * 8];
            bf16x8 a1 = *(const bf16x8*)&As[wm * 32 + 16 + l15][quad * 8];
            bf16x8 b0 = *(const bf16x8*)&Bs[wn * 32 + l15][quad * 8];
            bf16x8 b1 = *(const bf16x8*)&Bs[wn * 32 + 16 + l15][quad * 8];
            acc[0][0] = __builtin_amdgcn_mfma_f32_16x16x32_bf16(a0, b0, acc[0][0], 0, 0, 0);
            acc[0][1] = __builtin_amdgcn_mfma_f32_16x16x32_bf16(a0, b1, acc[0][1], 0, 0, 0);
            acc[1][0] = __builtin_amdgcn_mfma_f32_16x16x32_bf16(a1, b0, acc[1][0], 0, 0, 0);
            acc[1][1] = __builtin_amdgcn_mfma_f32_16x16x32_bf16(a1, b1, acc[1][1], 0, 0, 0);
        }
        for (int ai = 0; ai < 2; ++ai)
            for (int bi = 0; bi < 2; ++bi) {
                int row = m0 + wm * 32 + ai * 16 + quad * 4;
                int col = n0 + wn * 32 + bi * 16 + l15;
                for (int r = 0; r < 4; ++r) C[(row + r) * 512 + col] = f2b(acc[ai][bi][r]);
            }
        return;
    }
    // ---- persistent LSTM (identical to r9 k_lstm4) ----
    int k0 = blockIdx.x * 8;
    int lane = tid & 63, w = tid >> 6;
    int mi = w >> 1, ni = w & 1;
    int l15 = lane & 15, quad = lane >> 4;
    int row = tid >> 3, seg = tid & 7;
    {
        int j = (row >> 3) * 512 + k0 + (row & 7);
        const uint4* src = (const uint4*)(w_hh_bf + j * 512);
        for (int i = 0; i < 8; ++i)
            *(uint4*)&Bw[row][(seg + 8 * i) * 8] = src[seg + 8 * i];
    }
    if (row < 16) {
        if (row < 8) {
            const uint4* src = (const uint4*)(wq_hop_T + (k0 + row) * 512);
            for (int i = 0; i < 8; ++i)
                *(uint4*)&Wq[row][(seg + 8 * i) * 8] = src[seg + 8 * i];
        } else {
            uint4 z = {0, 0, 0, 0};
            for (int i = 0; i < 8; ++i)
                *(uint4*)&Wq[row][(seg + 8 * i) * 8] = z;
        }
    }
    for (int i = 0; i < 8; ++i) {
        int col = (seg + 8 * i) * 8;
        float4 f0 = *(const float4*)(init_h + col);
        float4 f1 = *(const float4*)(init_h + col + 4);
        uint4 p;
        p.x = pack2(f0.x, f0.y);
        p.y = pack2(f0.z, f0.w);
        p.z = pack2(f1.x, f1.y);
        p.w = pack2(f1.z, f1.w);
        *(uint4*)&Ah[row][col] = p;
    }
    float c = init_c[k0 + seg];
    float xcur0, xcur1, xcur2, xcur3;
    {
        const float* p = xw + (row << 5) * 2048 + k0 + seg;
        xcur0 = p[0]; xcur1 = p[512]; xcur2 = p[1024]; xcur3 = p[1536];
    }
    __syncthreads();
    for (int t = 0; t < 32; ++t) {
        f32x4 acc = {};
#pragma unroll
        for (int kc = 0; kc < 16; ++kc) {
            bf16x8 a = *(const bf16x8*)&Ah[mi * 16 + l15][kc * 32 + quad * 8];
            bf16x8 b = *(const bf16x8*)&Bw[ni * 16 + l15][kc * 32 + quad * 8];
            acc = __builtin_amdgcn_mfma_f32_16x16x32_bf16(a, b, acc, 0, 0, 0);
        }
        {
            int r0 = mi * 16 + quad * 4, col = ni * 16 + l15;
            for (int r = 0; r < 4; ++r) gl[r0 + r][col] = acc[r];
        }
        __syncthreads();  // #1
        int b = row, kg = k0 + seg;
        float gi = gl[b][seg] + xcur0;
        float gf = gl[b][8 + seg] + xcur1;
        float gg = gl[b][16 + seg] + xcur2;
        float go = gl[b][24 + seg] + xcur3;
        float cnew = fast_sig(gf) * c + fast_sig(gi) * fast_tanh(gg);
        c = cnew;
        float h = fast_sig(go) * fast_tanh(cnew);
        u16 hb = f2b(h);
        gbuf[b][seg] = hb;
        __syncthreads();  // #2
        if (tid < 64) {
            int b2 = tid >> 1, half = tid & 1;
            u64 v = *(const u64*)&gbuf[b2][half * 4];
            u64* dst = hbuf + (t & 1) * 4096 + blockIdx.x * 64 + tid;
            __hip_atomic_store(dst, v, __ATOMIC_RELAXED, __HIP_MEMORY_SCOPE_AGENT);
            __builtin_amdgcn_s_waitcnt(0);
            if (tid == 0)
                __hip_atomic_store(&flags[blockIdx.x * FLAG_STRIDE], (unsigned int)(t + 1),
                                   __ATOMIC_RELAXED, __HIP_MEMORY_SCOPE_AGENT);
            while (true) {
                unsigned int f = __hip_atomic_load(&flags[tid * FLAG_STRIDE],
                                                   __ATOMIC_RELAXED, __HIP_MEMORY_SCOPE_AGENT);
                if (__ballot(f > (unsigned int)t) == ~0ull) break;
                __builtin_amdgcn_s_sleep(1);
            }
        } else if (t > 0 && w <= 2) {
            int mt = w - 1;
            f32x4 acc2 = {};
#pragma unroll
            for (int kc = 0; kc < 16; ++kc) {
                bf16x8 a = *(const bf16x8*)&Ah[mt * 16 + l15][kc * 32 + quad * 8];
                bf16x8 bq = *(const bf16x8*)&Wq[l15][kc * 32 + quad * 8];
                acc2 = __builtin_amdgcn_mfma_f32_16x16x32_bf16(a, bq, acc2, 0, 0, 0);
            }
            if (l15 < 8) {
                int bidx = mt * 16 + quad * 4;
                for (int r = 0; r < 4; ++r)
                    qbuf[(((bidx + r) << 5) + (t - 1)) * 512 + k0 + l15] = acc2[r];
            }
        }
        __syncthreads();  // #3
        int tn = (t < 31) ? t + 1 : 31;
        float xn0, xn1, xn2, xn3;
        {
            const float* p = xw + ((row << 5) + tn) * 2048 + k0 + seg;
            xn0 = p[0]; xn1 = p[512]; xn2 = p[1024]; xn3 = p[1536];
        }
        {
            const u64* src = hbuf + (t & 1) * 4096;
#pragma unroll
            for (int i = 0; i < 8; ++i) {
                int bid2 = seg + 8 * i;
                u64 v0 = __hip_atomic_load(&src[bid2 * 64 + row * 2], __ATOMIC_RELAXED,
                                           __HIP_MEMORY_SCOPE_AGENT);
                u64 v1 = __hip_atomic_load(&src[bid2 * 64 + row * 2 + 1], __ATOMIC_RELAXED,
                                           __HIP_MEMORY_SCOPE_AGENT);
                *(u64*)&Ah[row][bid2 * 8] = v0;
                *(u64*)&Ah[row][bid2 * 8 + 4] = v1;
            }
        }
        __syncthreads();  // #4
        xcur0 = xn0; xcur1 = xn1; xcur2 = xn2; xcur3 = xn3;
    }
    // epilogue: q2 for t=31 (Ah = h(32) = query[31])
    if (w == 1 || w == 2) {
        int mt = w - 1;
        f32x4 acc2 = {};
#pragma unroll
        for (int kc = 0; kc < 16; ++kc) {
            bf16x8 a = *(const bf16x8*)&Ah[mt * 16 + l15][kc * 32 + quad * 8];
            bf16x8 bq = *(const bf16x8*)&Wq[l15][kc * 32 + quad * 8];
            acc2 = __builtin_amdgcn_mfma_f32_16x16x32_bf16(a, bq, acc2, 0, 0, 0);
        }
        if (l15 < 8) {
            int bidx = mt * 16 + quad * 4;
            for (int r = 0; r < 4; ++r)
                qbuf[(((bidx + r) << 5) + 31) * 512 + k0 + l15] = acc2[r];
        }
    }
}

// ---------------- fused hop attention --------------------------------------
__launch_bounds__(256)
__global__ void k_hop(const u16* __restrict__ feat, const float* __restrict__ q,
                      const float* __restrict__ v, const int* __restrict__ mem_sizes,
                      u16* __restrict__ nq) {
    __shared__ float qs[512];
    __shared__ float vs[512];
    __shared__ float sc[128];
    __shared__ float ns[128];
    int bt = blockIdx.x;
    int b = bt >> 5;
    int tid = threadIdx.x;
    qs[tid] = q[bt * 512 + tid];
    qs[tid + 256] = q[bt * 512 + 256 + tid];
    vs[tid] = v[tid];
    vs[tid + 256] = v[tid + 256];
    __syncthreads();
    int lane = tid & 63, w = tid >> 6;
    int h0 = lane * 8;
    float qv[8], vv[8];
#pragma unroll
    for (int i = 0; i < 8; ++i) { qv[i] = qs[h0 + i]; vv[i] = vs[h0 + i]; }
    const u16* fb = feat + (size_t)b * 128 * 512;
    for (int i = 0; i < 32; ++i) {
        int n = w * 32 + i;
        uint4 fv = *(const uint4*)(fb + n * 512 + h0);
        float fr[8];
        fr[0] = b2f((u16)(fv.x & 0xFFFF)); fr[1] = b2f((u16)(fv.x >> 16));
        fr[2] = b2f((u16)(fv.y & 0xFFFF)); fr[3] = b2f((u16)(fv.y >> 16));
        fr[4] = b2f((u16)(fv.z & 0xFFFF)); fr[5] = b2f((u16)(fv.z >> 16));
        fr[6] = b2f((u16)(fv.w & 0xFFFF)); fr[7] = b2f((u16)(fv.w >> 16));
        float a = 0.f;
#pragma unroll
        for (int jj = 0; jj < 8; ++jj) a += fast_tanh(fr[jj] + qv[jj]) * vv[jj];
        for (int off = 1; off < 64; off <<= 1) a += __shfl_xor(a, off);
        if (lane == 0) sc[n] = a;
    }
    __syncthreads();
    if (tid < 64) {
        int ms = mem_sizes[b];
        float s0 = (tid < ms) ? sc[tid] : -1e30f;
        float s1 = (tid + 64 < ms) ? sc[tid + 64] : -1e30f;
        float m = fmaxf(s0, s1);
        for (int off = 1; off < 64; off <<= 1) m = fmaxf(m, __shfl_xor(m, off));
        float e0 = __expf(s0 - m), e1 = __expf(s1 - m);
        float s = e0 + e1;
        for (int off = 1; off < 64; off <<= 1) s += __shfl_xor(s, off);
        float r = fast_rcp(s);
        ns[tid] = e0 * r;
        ns[tid + 64] = e1 * r;
    }
    __syncthreads();
    float a0 = 0.f, a1 = 0.f;
    int hc = tid * 2;
    for (int n = 0; n < 128; ++n) {
        float f = ns[n];
        unsigned int pv = *(const unsigned int*)(fb + n * 512 + hc);
        a0 += f * b2f((u16)(pv & 0xFFFF));
        a1 += f * b2f((u16)(pv >> 16));
    }
    ((unsigned int*)nq)[bt * 256 + tid] = pack2(a0, a1);
}

// ---------------- final scores -> out (f32) --------------------------------
__launch_bounds__(256)
__global__ void k_score(const u16* __restrict__ feat, const float* __restrict__ q,
                        const float* __restrict__ v, float* __restrict__ outp) {
    __shared__ float qs[512];
    __shared__ float vs[512];
    __shared__ float sc[128];
    int bt = blockIdx.x;
    int b = bt >> 5;
    int tid = threadIdx.x;
    qs[tid] = q[bt * 512 + tid];
    qs[tid + 256] = q[bt * 512 + 256 + tid];
    vs[tid] = v[tid];
    vs[tid + 256] = v[tid + 256];
    __syncthreads();
    int lane = tid & 63, w = tid >> 6;
    int h0 = lane * 8;
    float qv[8], vv[8];
#pragma unroll
    for (int i = 0; i < 8; ++i) { qv[i] = qs[h0 + i]; vv[i] = vs[h0 + i]; }
    const u16* fb = feat + (size_t)b * 128 * 512;
    for (int i = 0; i < 32; ++i) {
        int n = w * 32 + i;
        uint4 fv = *(const uint4*)(fb + n * 512 + h0);
        float fr[8];
        fr[0] = b2f((u16)(fv.x & 0xFFFF)); fr[1] = b2f((u16)(fv.x >> 16));
        fr[2] = b2f((u16)(fv.y & 0xFFFF)); fr[3] = b2f((u16)(fv.y >> 16));
        fr[4] = b2f((u16)(fv.z & 0xFFFF)); fr[5] = b2f((u16)(fv.z >> 16));
        fr[6] = b2f((u16)(fv.w & 0xFFFF)); fr[7] = b2f((u16)(fv.w >> 16));
        float a = 0.f;
#pragma unroll
        for (int jj = 0; jj < 8; ++jj) a += fast_tanh(fr[jj] + qv[jj]) * vv[jj];
        for (int off = 1; off < 64; off <<= 1) a += __shfl_xor(a, off);
        if (lane == 0) sc[n] = a;
    }
    __syncthreads();
    if (tid < 128) outp[bt * 128 + tid] = sc[tid];
}

extern "C" void kernel_launch(void* const* d_in, const int* in_sizes, int n_in,
                              void* d_out, int out_size, void* d_ws, size_t ws_size,
                              hipStream_t stream) {
    (void)in_sizes; (void)n_in; (void)out_size; (void)ws_size;
    const float* attn_mem = (const float*)d_in[0];
    const int* mem_sizes = (const int*)d_in[1];
    const float* lstm_in = (const float*)d_in[2];
    const float* init_h = (const float*)d_in[3];
    const float* init_c = (const float*)d_in[4];
    const float* init_i = (const float*)d_in[5];
    const float* w_ih = (const float*)d_in[6];
    const float* w_hh = (const float*)d_in[7];
    const float* b_ih = (const float*)d_in[8];
    const float* b_hh = (const float*)d_in[9];
    const float* attn_wm = (const float*)d_in[10];
    const float* attn_wq = (const float*)d_in[11];
    const float* attn_v = (const float*)d_in[12];
    const float* hop_wm = (const float*)d_in[13];
    const float* hop_wq = (const float*)d_in[14];
    const float* hop_v = (const float*)d_in[15];
    float* out = (float*)d_out;

    char* ws = (char*)d_ws;
    size_t off = 0;
    auto alloc = [&](size_t bytes) {
        void* p = ws + off;
        off += (bytes + 255) & ~(size_t)255;
        return p;
    };
    u16* amem_bf = (u16*)alloc(4096 * 512 * 2);
    u16* xfull_bf = (u16*)alloc(1024 * 512 * 2);
    u16* wih_bf = (u16*)alloc(2048 * 512 * 2);
    u16* whh_bf = (u16*)alloc(2048 * 512 * 2);
    u16* WmT_hop = (u16*)alloc(512 * 512 * 2);
    u16* WmT_attn = (u16*)alloc(512 * 512 * 2);
    u16* WqT_hop = (u16*)alloc(512 * 512 * 2);
    u16* WqT_attn = (u16*)alloc(512 * 512 * 2);
    float* xw = (float*)alloc(1024 * 2048 * 4);
    u16* hop_feat = (u16*)alloc(4096 * 512 * 2);
    u16* attn_feat = (u16*)alloc(4096 * 512 * 2);
    u64* hbuf = (u64*)alloc(2 * 64 * 64 * 8);
    unsigned int* flags = (unsigned int*)alloc(64 * FLAG_STRIDE * 4);
    float* qbuf = (float*)alloc(1024 * 512 * 4);
    u16* nq = (u16*)alloc(1024 * 512 * 2);

    k_prep<<<5632, 256, 0, stream>>>(attn_mem, amem_bf, w_ih, wih_bf, w_hh, whh_bf,
                                     lstm_in, init_i, xfull_bf,
                                     attn_wm, hop_wm, hop_wq, attn_wq,
                                     WmT_attn, WmT_hop, WqT_hop, WqT_attn, flags);
    k_xw<<<512, 256, 0, stream>>>(xfull_bf, wih_bf, xw, b_ih, b_hh);
    k_lstm5<<<1088, 256, 0, stream>>>(whh_bf, xw, init_h, init_c, WqT_hop, qbuf, hbuf, flags,
                                      amem_bf, WmT_hop, WmT_attn, hop_feat, attn_feat);
    k_hop<<<1024, 256, 0, stream>>>(hop_feat, qbuf, hop_v, mem_sizes, nq);
    k_gemm<<<dim3(8, 16), 256, 0, stream>>>(nq, WqT_attn, qbuf, 512);
    k_score<<<1024, 256, 0, stream>>>(attn_feat, qbuf, attn_v, out);
}